// Round 1
// baseline (372.708 us; speedup 1.0000x reference)
//
#include <hip/hip_runtime.h>
#include <hip/hip_bf16.h>

constexpr int kS   = 32;
constexpr int kB   = 256;
constexpr int kIN  = 1024;
constexpr int kOUT = 1024;
constexpr int BN   = 32;    // o-cols per block (2 MFMA col-frags per wave)

typedef __bf16 v8bf __attribute__((ext_vector_type(8)));
typedef float  v4f  __attribute__((ext_vector_type(4)));

__device__ __forceinline__ float softplus_f(float x) {
    return fmaxf(x, 0.0f) + log1pf(expf(-fabsf(x)));
}
__device__ __forceinline__ unsigned int bfbits(float x) {
    __bf16 h = (__bf16)x;
    unsigned short u;
    __builtin_memcpy(&u, &h, 2);
    return (unsigned int)u;
}
__device__ __forceinline__ float asf(unsigned int u) {
    float f; __builtin_memcpy(&f, &u, 4); return f;
}

// pack (bf16(mu) low, bf16(softplus(rho)) high) into u32 per weight element
__global__ void sigma_pack(const float* __restrict__ mu, const float* __restrict__ rho,
                           uint4* __restrict__ ms) {
    int gid = blockIdx.x * blockDim.x + threadIdx.x;  // 4 elems/thread
    float4 m = reinterpret_cast<const float4*>(mu)[gid];
    float4 r = reinterpret_cast<const float4*>(rho)[gid];
    uint4 o;
    o.x = bfbits(m.x) | (bfbits(softplus_f(r.x)) << 16);
    o.y = bfbits(m.y) | (bfbits(softplus_f(r.y)) << 16);
    o.z = bfbits(m.z) | (bfbits(softplus_f(r.z)) << 16);
    o.w = bfbits(m.w) | (bfbits(softplus_f(r.w)) << 16);
    ms[gid] = o;
}

// cast X fp32 -> bf16 workspace, 8 elems/thread
__global__ void xcast_kernel(const float* __restrict__ X, __bf16* __restrict__ Xb) {
    size_t i = ((size_t)blockIdx.x * blockDim.x + threadIdx.x) * 8;
    float4 a = *reinterpret_cast<const float4*>(X + i);
    float4 b = *reinterpret_cast<const float4*>(X + i + 4);
    v8bf r;
    r[0] = (__bf16)a.x; r[1] = (__bf16)a.y; r[2] = (__bf16)a.z; r[3] = (__bf16)a.w;
    r[4] = (__bf16)b.x; r[5] = (__bf16)b.y; r[6] = (__bf16)b.z; r[7] = (__bf16)b.w;
    *reinterpret_cast<v8bf*>(Xb + i) = r;
}

// LDS-free, (nearly) barrier-free streaming MFMA GEMM.
// Block = (s, M=256, N=32): 4 waves, wave wv owns rows [wv*64, wv*64+64).
// Per k-tile (BK=32): A-frags straight from L2-resident bf16 X workspace;
// B-frags (per-sample W) built in registers from eps (HBM stream) + packed
// (mu,sigma). No LDS -> no bank conflicts, no per-tile barriers; occupancy
// 4 blocks/CU (16 waves) via __launch_bounds__(256,4), LDS=0.
template<bool XBF>
__global__ __launch_bounds__(256, 4) void dv_main(
        const void* __restrict__ Xv,            // [S][B][IN] bf16 (XBF) or fp32
        const unsigned int* __restrict__ MS,    // [OUT][IN] packed (mu,sigma)
        const float* __restrict__ Ew,           // [S][OUT][IN]
        const float* __restrict__ Bmu,          // [OUT]
        const float* __restrict__ Brho,         // [OUT]
        const float* __restrict__ Eb,           // [S][OUT]
        float* __restrict__ O)                  // [S][B][OUT]
{
    const int tid = threadIdx.x;
    const int bb  = blockIdx.x;
    const int xcd = bb & 7;
    const int jj  = bb >> 3;                   // 0..127
    const int s   = (xcd << 2) | (jj & 3);     // 4 s-values per XCD -> X L2-resident
    const int o_base = (jj >> 2) * BN;         // 0..992

    const int lane = tid & 63, wv = tid >> 6;
    const int lr = lane & 15, kg = lane >> 4;

    const size_t R16 = (size_t)16 * kIN;       // 16 rows

    // lane-resolved base pointers (frag layout: lane(lr,kg) holds row lr, k kg*8..+8)
    const float*        Eg  = Ew + ((size_t)s * kOUT + o_base + lr) * kIN + kg * 8;
    const unsigned int* MSg = MS + (size_t)(o_base + lr) * kIN + kg * 8;
    const __bf16* Xb = (const __bf16*)Xv + ((size_t)s * kB + wv * 64 + lr) * kIN + kg * 8;
    const float*  Xg = (const float*)Xv  + ((size_t)s * kB + wv * 64 + lr) * kIN + kg * 8;

    v4f acc[4][2] = {};

    for (int kt = 0; kt < 32; ++kt) {
        const int k0 = kt * 32;

        // ---- A fragments: 4 x 16B loads (L2-resident bf16 X) ----
        v8bf a[4];
        if constexpr (XBF) {
            #pragma unroll
            for (int mf = 0; mf < 4; ++mf)
                a[mf] = *reinterpret_cast<const v8bf*>(Xb + mf * R16 + k0);
        } else {
            #pragma unroll
            for (int mf = 0; mf < 4; ++mf) {
                float4 x0 = *reinterpret_cast<const float4*>(Xg + mf * R16 + k0);
                float4 x1 = *reinterpret_cast<const float4*>(Xg + mf * R16 + k0 + 4);
                v8bf t;
                t[0] = (__bf16)x0.x; t[1] = (__bf16)x0.y;
                t[2] = (__bf16)x0.z; t[3] = (__bf16)x0.w;
                t[4] = (__bf16)x1.x; t[5] = (__bf16)x1.y;
                t[6] = (__bf16)x1.z; t[7] = (__bf16)x1.w;
                a[mf] = t;
            }
        }

        // ---- B-side raw loads: eps (HBM stream) + packed mu/sigma (L2) ----
        float4 e0[2], e1[2]; uint4 p0[2], p1[2];
        #pragma unroll
        for (int nf = 0; nf < 2; ++nf) {
            const float*        ep = Eg  + nf * R16 + k0;
            const unsigned int* mp = MSg + nf * R16 + k0;
            e0[nf] = *reinterpret_cast<const float4*>(ep);
            e1[nf] = *reinterpret_cast<const float4*>(ep + 4);
            p0[nf] = *reinterpret_cast<const uint4*>(mp);
            p1[nf] = *reinterpret_cast<const uint4*>(mp + 4);
        }

        // ---- build W fragments in registers: w = mu + sigma*eps -> bf16 ----
        v8bf b[2];
        #pragma unroll
        for (int nf = 0; nf < 2; ++nf) {
            b[nf][0] = (__bf16)fmaf(asf(p0[nf].x & 0xffff0000u), e0[nf].x, asf(p0[nf].x << 16));
            b[nf][1] = (__bf16)fmaf(asf(p0[nf].y & 0xffff0000u), e0[nf].y, asf(p0[nf].y << 16));
            b[nf][2] = (__bf16)fmaf(asf(p0[nf].z & 0xffff0000u), e0[nf].z, asf(p0[nf].z << 16));
            b[nf][3] = (__bf16)fmaf(asf(p0[nf].w & 0xffff0000u), e0[nf].w, asf(p0[nf].w << 16));
            b[nf][4] = (__bf16)fmaf(asf(p1[nf].x & 0xffff0000u), e1[nf].x, asf(p1[nf].x << 16));
            b[nf][5] = (__bf16)fmaf(asf(p1[nf].y & 0xffff0000u), e1[nf].y, asf(p1[nf].y << 16));
            b[nf][6] = (__bf16)fmaf(asf(p1[nf].z & 0xffff0000u), e1[nf].z, asf(p1[nf].z << 16));
            b[nf][7] = (__bf16)fmaf(asf(p1[nf].w & 0xffff0000u), e1[nf].w, asf(p1[nf].w << 16));
        }

        // ---- 8 MFMAs ----
        #pragma unroll
        for (int mf = 0; mf < 4; ++mf)
            #pragma unroll
            for (int nf = 0; nf < 2; ++nf)
                acc[mf][nf] = __builtin_amdgcn_mfma_f32_16x16x32_bf16(
                    a[mf], b[nf], acc[mf][nf], 0, 0, 0);

        // bound wave drift so the 4 waves' shared eps lines stay L1/L2-hot
        if ((kt & 7) == 7) __syncthreads();
    }

    // ---- epilogue: inline-sampled bias + nontemporal store ----
    float bias[2];
    #pragma unroll
    for (int nf = 0; nf < 2; ++nf) {
        int o = o_base + nf * 16 + lr;
        bias[nf] = fmaf(softplus_f(Brho[o]), Eb[(size_t)s * kOUT + o], Bmu[o]);
    }
    #pragma unroll
    for (int mf = 0; mf < 4; ++mf) {
        #pragma unroll
        for (int rr = 0; rr < 4; ++rr) {
            int mrow = wv * 64 + mf * 16 + kg * 4 + rr;  // C/D: row=(lane>>4)*4+reg
            float* orow = O + ((size_t)s * kB + mrow) * kOUT + o_base;
            #pragma unroll
            for (int nf = 0; nf < 2; ++nf)
                __builtin_nontemporal_store(acc[mf][nf][rr] + bias[nf],
                                            orow + nf * 16 + lr);  // col = lane&15
        }
    }
}

extern "C" void kernel_launch(void* const* d_in, const int* in_sizes, int n_in,
                              void* d_out, int out_size, void* d_ws, size_t ws_size,
                              hipStream_t stream) {
    const float* input = (const float*)d_in[0];
    const float* w_mu  = (const float*)d_in[1];
    const float* w_rho = (const float*)d_in[2];
    const float* b_mu  = (const float*)d_in[3];
    const float* b_rho = (const float*)d_in[4];
    const float* eps_w = (const float*)d_in[5];
    const float* eps_b = (const float*)d_in[6];
    float* out = (float*)d_out;

    const size_t ms_bytes  = (size_t)kOUT * kIN * 4;                 //  4 MB
    const size_t xbf_bytes = (size_t)kS * kB * kIN * sizeof(__bf16); // 16 MB
    const bool use_xbf = ws_size >= ms_bytes + xbf_bytes;

    unsigned int* ms = (unsigned int*)d_ws;
    __bf16* xbf = (__bf16*)((char*)d_ws + ms_bytes);

    sigma_pack<<<dim3((kOUT * kIN) / (256 * 4)), 256, 0, stream>>>(w_mu, w_rho, (uint4*)ms);

    dim3 grid(kS * (kOUT / BN));   // 1024 blocks, XCD-swizzled, 4 blocks/CU
    if (use_xbf) {
        xcast_kernel<<<dim3((size_t)kS * kB * kIN / (256 * 8)), 256, 0, stream>>>(input, xbf);
        dv_main<true><<<grid, 256, 0, stream>>>(xbf, ms, eps_w, b_mu, b_rho, eps_b, out);
    } else {
        dv_main<false><<<grid, 256, 0, stream>>>(input, ms, eps_w, b_mu, b_rho, eps_b, out);
    }
}

// Round 3
// 309.161 us; speedup vs baseline: 1.2055x; 1.2055x over previous
//
#include <hip/hip_runtime.h>
#include <hip/hip_bf16.h>

constexpr int kS   = 32;
constexpr int kB   = 256;
constexpr int kIN  = 1024;
constexpr int kOUT = 1024;
constexpr int BN   = 32;            // o-cols per block (2 MFMA col-frags per wave)
constexpr int CK   = 64;            // k per W-chunk
constexpr int NCH  = kIN / CK;      // 16 chunks

typedef __bf16 v4bf __attribute__((ext_vector_type(4)));
typedef __bf16 v8bf __attribute__((ext_vector_type(8)));
typedef float  v4f  __attribute__((ext_vector_type(4)));

__device__ __forceinline__ float softplus_f(float x) {
    return fmaxf(x, 0.0f) + log1pf(expf(-fabsf(x)));
}
__device__ __forceinline__ unsigned int bfbits(float x) {
    __bf16 h = (__bf16)x;
    unsigned short u;
    __builtin_memcpy(&u, &h, 2);
    return (unsigned int)u;
}
__device__ __forceinline__ float asf(unsigned int u) {
    float f; __builtin_memcpy(&f, &u, 4); return f;
}

// pack (bf16(mu) low, bf16(softplus(rho)) high) into u32 per weight element
__global__ void sigma_pack(const float* __restrict__ mu, const float* __restrict__ rho,
                           uint4* __restrict__ ms) {
    int gid = blockIdx.x * blockDim.x + threadIdx.x;  // 4 elems/thread
    float4 m = reinterpret_cast<const float4*>(mu)[gid];
    float4 r = reinterpret_cast<const float4*>(rho)[gid];
    uint4 o;
    o.x = bfbits(m.x) | (bfbits(softplus_f(r.x)) << 16);
    o.y = bfbits(m.y) | (bfbits(softplus_f(r.y)) << 16);
    o.z = bfbits(m.z) | (bfbits(softplus_f(r.z)) << 16);
    o.w = bfbits(m.w) | (bfbits(softplus_f(r.w)) << 16);
    ms[gid] = o;
}

// cast X fp32 -> bf16 workspace, 8 elems/thread
__global__ void xcast_kernel(const float* __restrict__ X, __bf16* __restrict__ Xb) {
    size_t i = ((size_t)blockIdx.x * blockDim.x + threadIdx.x) * 8;
    float4 a = *reinterpret_cast<const float4*>(X + i);
    float4 b = *reinterpret_cast<const float4*>(X + i + 4);
    v8bf r;
    r[0] = (__bf16)a.x; r[1] = (__bf16)a.y; r[2] = (__bf16)a.z; r[3] = (__bf16)a.w;
    r[4] = (__bf16)b.x; r[5] = (__bf16)b.y; r[6] = (__bf16)b.z; r[7] = (__bf16)b.w;
    *reinterpret_cast<v8bf*>(Xb + i) = r;
}

// v3 (resubmit; previous round was an infra failure, not a kernel failure):
// hybrid of r0 (coalesced cooperative eps staging) and r1 (LDS-free X frags).
// Block = (s, M=256, N=32), 4 waves. W chunks (32 rows x CK=64) double-buffered
// in 8KB swizzled LDS; eps/MS for chunk c+1 loaded into regs at the TOP of
// chunk c's MFMA phase (issue-early) and converted/ds_written at the bottom
// (write-late) -> HBM latency hides under MFMA+X-loads, one barrier per chunk
// with nothing in flight at the drain. X frags read direct from L2-resident
// bf16 workspace (layout verified in r1). 4 blocks/CU, whole grid co-resident.
template<bool XBF>
__global__ __launch_bounds__(256, 4) void dv_main(
        const void* __restrict__ Xv,            // [S][B][IN] bf16 (XBF) or fp32
        const unsigned int* __restrict__ MS,    // [OUT][IN] packed (mu,sigma)
        const float* __restrict__ Ew,           // [S][OUT][IN]
        const float* __restrict__ Bmu,          // [OUT]
        const float* __restrict__ Brho,         // [OUT]
        const float* __restrict__ Eb,           // [S][OUT]
        float* __restrict__ O)                  // [S][B][OUT]
{
    __shared__ __attribute__((aligned(16))) __bf16 Wc[2][BN * CK];  // 2 x 4 KB

    const int tid = threadIdx.x;
    const int bb  = blockIdx.x;
    const int xcd = bb & 7;
    const int jj  = bb >> 3;                   // 0..127
    const int s   = (xcd << 2) | (jj & 3);     // 4 s-values per XCD -> X L2-resident
    const int o_base = (jj >> 2) * BN;         // 0..992

    const int lane = tid & 63, wv = tid >> 6;
    const int lr = lane & 15, kg = lane >> 4;

    const size_t R16 = (size_t)16 * kIN;       // 16 rows

    // A-frag base (r1-verified): lane(lr,kg) holds row wv*64+mf*16+lr, k kg*8..+8
    const __bf16* Xb = (const __bf16*)Xv + ((size_t)s * kB + wv * 64 + lr) * kIN + kg * 8;
    const float*  Xg = (const float*)Xv  + ((size_t)s * kB + wv * 64 + lr) * kIN + kg * 8;

    // staging mapping: thread covers rows {srow, srow+16} of the 32-row chunk,
    // 4 consecutive k each -> per-instr: 16 rows x 256B contiguous (coalesced)
    const int srow = tid >> 4;                 // 0..15
    const int scol = (tid & 15) * 4;           // 0..60
    const float*        Eg2  = Ew + ((size_t)s * kOUT + o_base) * kIN;
    const unsigned int* MSg2 = MS + (size_t)o_base * kIN;

    v4f acc[4][2] = {};

    // ---- stage chunk 0 (synchronous prologue) ----
    float4 ce[2]; uint4 cp[2];
    #pragma unroll
    for (int b2 = 0; b2 < 2; ++b2) {
        int r = b2 * 16 + srow;
        ce[b2] = *reinterpret_cast<const float4*>(Eg2 + (size_t)r * kIN + scol);
        cp[b2] = *reinterpret_cast<const uint4*>(MSg2 + (size_t)r * kIN + scol);
    }
    #pragma unroll
    for (int b2 = 0; b2 < 2; ++b2) {
        int r = b2 * 16 + srow;
        v4bf w;
        w[0] = (__bf16)fmaf(asf(cp[b2].x & 0xffff0000u), ce[b2].x, asf(cp[b2].x << 16));
        w[1] = (__bf16)fmaf(asf(cp[b2].y & 0xffff0000u), ce[b2].y, asf(cp[b2].y << 16));
        w[2] = (__bf16)fmaf(asf(cp[b2].z & 0xffff0000u), ce[b2].z, asf(cp[b2].z << 16));
        w[3] = (__bf16)fmaf(asf(cp[b2].w & 0xffff0000u), ce[b2].w, asf(cp[b2].w << 16));
        int off = (r * 128 + scol * 2) ^ ((r & 7) << 4);    // XOR-swizzle (T2 form)
        *reinterpret_cast<v4bf*>((char*)&Wc[0][0] + off) = w;
    }
    __syncthreads();

    int cur = 0;
    for (int c = 0; c < NCH; ++c) {
        // ---- issue-early: eps+MS reg loads for chunk c+1 (in flight all phase) ----
        float4 ne[2]; uint4 np[2];
        if (c + 1 < NCH) {
            const int ck = (c + 1) * CK;
            #pragma unroll
            for (int b2 = 0; b2 < 2; ++b2) {
                int r = b2 * 16 + srow;
                ne[b2] = *reinterpret_cast<const float4*>(Eg2 + (size_t)r * kIN + ck + scol);
                np[b2] = *reinterpret_cast<const uint4*>(MSg2 + (size_t)r * kIN + ck + scol);
            }
        }

        // ---- MFMA phase: 2 k-tiles from Wc[cur] + direct-global X ----
        #pragma unroll
        for (int ktl = 0; ktl < 2; ++ktl) {
            const int k0 = (c * 2 + ktl) * 32;

            v8bf a[4];
            if constexpr (XBF) {
                #pragma unroll
                for (int mf = 0; mf < 4; ++mf)
                    a[mf] = *reinterpret_cast<const v8bf*>(Xb + mf * R16 + k0);
            } else {
                #pragma unroll
                for (int mf = 0; mf < 4; ++mf) {
                    float4 x0 = *reinterpret_cast<const float4*>(Xg + mf * R16 + k0);
                    float4 x1 = *reinterpret_cast<const float4*>(Xg + mf * R16 + k0 + 4);
                    v8bf t;
                    t[0] = (__bf16)x0.x; t[1] = (__bf16)x0.y;
                    t[2] = (__bf16)x0.z; t[3] = (__bf16)x0.w;
                    t[4] = (__bf16)x1.x; t[5] = (__bf16)x1.y;
                    t[6] = (__bf16)x1.z; t[7] = (__bf16)x1.w;
                    a[mf] = t;
                }
            }

            v8bf b[2];
            #pragma unroll
            for (int nf = 0; nf < 2; ++nf) {
                int r = nf * 16 + lr;
                int off = (r * 128 + ktl * 64 + kg * 16) ^ ((r & 7) << 4);
                b[nf] = *reinterpret_cast<const v8bf*>((const char*)&Wc[cur][0] + off);
            }

            #pragma unroll
            for (int mf = 0; mf < 4; ++mf)
                #pragma unroll
                for (int nf = 0; nf < 2; ++nf)
                    acc[mf][nf] = __builtin_amdgcn_mfma_f32_16x16x32_bf16(
                        a[mf], b[nf], acc[mf][nf], 0, 0, 0);
        }

        // ---- write-late: convert + ds_write next chunk, single barrier ----
        if (c + 1 < NCH) {
            #pragma unroll
            for (int b2 = 0; b2 < 2; ++b2) {
                int r = b2 * 16 + srow;
                v4bf w;
                w[0] = (__bf16)fmaf(asf(np[b2].x & 0xffff0000u), ne[b2].x, asf(np[b2].x << 16));
                w[1] = (__bf16)fmaf(asf(np[b2].y & 0xffff0000u), ne[b2].y, asf(np[b2].y << 16));
                w[2] = (__bf16)fmaf(asf(np[b2].z & 0xffff0000u), ne[b2].z, asf(np[b2].z << 16));
                w[3] = (__bf16)fmaf(asf(np[b2].w & 0xffff0000u), ne[b2].w, asf(np[b2].w << 16));
                int off = (r * 128 + scol * 2) ^ ((r & 7) << 4);
                *reinterpret_cast<v4bf*>((char*)&Wc[cur ^ 1][0] + off) = w;
            }
            __syncthreads();   // nothing left in flight here -> drain is free
            cur ^= 1;
        }
    }

    // ---- epilogue: inline-sampled bias + nontemporal store (r1-verified) ----
    float bias[2];
    #pragma unroll
    for (int nf = 0; nf < 2; ++nf) {
        int o = o_base + nf * 16 + lr;
        bias[nf] = fmaf(softplus_f(Brho[o]), Eb[(size_t)s * kOUT + o], Bmu[o]);
    }
    #pragma unroll
    for (int mf = 0; mf < 4; ++mf) {
        #pragma unroll
        for (int rr = 0; rr < 4; ++rr) {
            int mrow = wv * 64 + mf * 16 + kg * 4 + rr;  // C/D: row=(lane>>4)*4+reg
            float* orow = O + ((size_t)s * kB + mrow) * kOUT + o_base;
            #pragma unroll
            for (int nf = 0; nf < 2; ++nf)
                __builtin_nontemporal_store(acc[mf][nf][rr] + bias[nf],
                                            orow + nf * 16 + lr);  // col = lane&15
        }
    }
}

extern "C" void kernel_launch(void* const* d_in, const int* in_sizes, int n_in,
                              void* d_out, int out_size, void* d_ws, size_t ws_size,
                              hipStream_t stream) {
    const float* input = (const float*)d_in[0];
    const float* w_mu  = (const float*)d_in[1];
    const float* w_rho = (const float*)d_in[2];
    const float* b_mu  = (const float*)d_in[3];
    const float* b_rho = (const float*)d_in[4];
    const float* eps_w = (const float*)d_in[5];
    const float* eps_b = (const float*)d_in[6];
    float* out = (float*)d_out;

    const size_t ms_bytes  = (size_t)kOUT * kIN * 4;                 //  4 MB
    const size_t xbf_bytes = (size_t)kS * kB * kIN * sizeof(__bf16); // 16 MB
    const bool use_xbf = ws_size >= ms_bytes + xbf_bytes;

    unsigned int* ms = (unsigned int*)d_ws;
    __bf16* xbf = (__bf16*)((char*)d_ws + ms_bytes);

    sigma_pack<<<dim3((kOUT * kIN) / (256 * 4)), 256, 0, stream>>>(w_mu, w_rho, (uint4*)ms);

    dim3 grid(kS * (kOUT / BN));   // 1024 blocks, XCD-swizzled, 4 blocks/CU
    if (use_xbf) {
        xcast_kernel<<<dim3((size_t)kS * kB * kIN / (256 * 8)), 256, 0, stream>>>(input, xbf);
        dv_main<true><<<grid, 256, 0, stream>>>(xbf, ms, eps_w, b_mu, b_rho, eps_b, out);
    } else {
        dv_main<false><<<grid, 256, 0, stream>>>(input, ms, eps_w, b_mu, b_rho, eps_b, out);
    }
}

// Round 4
// 298.027 us; speedup vs baseline: 1.2506x; 1.0374x over previous
//
#include <hip/hip_runtime.h>
#include <hip/hip_bf16.h>

constexpr int kS   = 32;
constexpr int kB   = 256;
constexpr int kIN  = 1024;
constexpr int kOUT = 1024;
constexpr int BM   = 256;        // rows (all of B) per block
constexpr int BN   = 64;         // o-cols per block
constexpr int BK   = 32;         // k per tile (one MFMA K)
constexpr int NT   = kIN / BK;   // 32 tiles

typedef __bf16 v8bf __attribute__((ext_vector_type(8)));
typedef float  v4f  __attribute__((ext_vector_type(4)));

__device__ __forceinline__ float softplus_f(float x) {
    return fmaxf(x, 0.0f) + log1pf(expf(-fabsf(x)));
}
__device__ __forceinline__ unsigned int bfbits(float x) {
    __bf16 h = (__bf16)x;
    unsigned short u;
    __builtin_memcpy(&u, &h, 2);
    return (unsigned int)u;
}
__device__ __forceinline__ float asf(unsigned int u) {
    float f; __builtin_memcpy(&f, &u, 4); return f;
}

// pack (bf16(mu) low, bf16(softplus(rho)) high) into u32 per weight element
__global__ void sigma_pack(const float* __restrict__ mu, const float* __restrict__ rho,
                           uint4* __restrict__ ms) {
    int gid = blockIdx.x * blockDim.x + threadIdx.x;  // 4 elems/thread
    float4 m = reinterpret_cast<const float4*>(mu)[gid];
    float4 r = reinterpret_cast<const float4*>(rho)[gid];
    uint4 o;
    o.x = bfbits(m.x) | (bfbits(softplus_f(r.x)) << 16);
    o.y = bfbits(m.y) | (bfbits(softplus_f(r.y)) << 16);
    o.z = bfbits(m.z) | (bfbits(softplus_f(r.z)) << 16);
    o.w = bfbits(m.w) | (bfbits(softplus_f(r.w)) << 16);
    ms[gid] = o;
}

// cast X fp32 -> bf16 workspace, 8 elems/thread
__global__ void xcast_kernel(const float* __restrict__ X, __bf16* __restrict__ Xb) {
    size_t i = ((size_t)blockIdx.x * blockDim.x + threadIdx.x) * 8;
    float4 a = *reinterpret_cast<const float4*>(X + i);
    float4 b = *reinterpret_cast<const float4*>(X + i + 4);
    v8bf r;
    r[0] = (__bf16)a.x; r[1] = (__bf16)a.y; r[2] = (__bf16)a.z; r[3] = (__bf16)a.w;
    r[4] = (__bf16)b.x; r[5] = (__bf16)b.y; r[6] = (__bf16)b.z; r[7] = (__bf16)b.w;
    *reinterpret_cast<v8bf*>(Xb + i) = r;
}

// async 16B/lane global->LDS (no result VGPRs; lds dest = uniform base + lane*16)
#define GLDS16(g, l) __builtin_amdgcn_global_load_lds(                      \
    (const __attribute__((address_space(1))) void*)(g),                     \
    (__attribute__((address_space(3))) void*)(l), 16, 0, 0)

// v4: counted-vmcnt global_load_lds ring pipeline (T3+T4 discipline).
// Block = (s, M=256, N=64), 8 waves (4M x 2N), 512 threads. Per BK=32 tile:
// X (bf16, r0-verified quarter-swizzle), eps (fp32, XOR-swizzled via
// pre-swizzled global source), MS (packed mu/sigma, same swizzle) all staged
// by global_load_lds into a 3-deep LDS ring (96 KB). Raw s_barrier + asm
// s_waitcnt vmcnt(4) (never 0 mid-loop) keeps 2 tiles of loads permanently
// in flight; lgkmcnt(0) before each barrier closes the t+2 == t-1 (mod 3)
// buffer-reuse hazard. W = mu + sigma*eps built in-lane at the MFMA
// consumption point (no reg-staging for the compiler to sink).
template<bool XBF>
__global__ __launch_bounds__(512, 2) void dv_main(
        const void* __restrict__ Xv,            // [S][B][IN] bf16 (XBF) or fp32
        const unsigned int* __restrict__ MS,    // [OUT][IN] packed (mu,sigma)
        const float* __restrict__ Ew,           // [S][OUT][IN]
        const float* __restrict__ Bmu,          // [OUT]
        const float* __restrict__ Brho,         // [OUT]
        const float* __restrict__ Eb,           // [S][OUT]
        float* __restrict__ O)                  // [S][B][OUT]
{
    __shared__ __attribute__((aligned(16))) __bf16       Xs[3][BM * BK];   // 3 x 16 KB
    __shared__ __attribute__((aligned(16))) float        Epb[3][BN * BK];  // 3 x  8 KB
    __shared__ __attribute__((aligned(16))) unsigned int Msb[3][BN * BK];  // 3 x  8 KB

    const int tid = threadIdx.x, bb = blockIdx.x;
    const int xcd = bb & 7;
    const int jj  = bb >> 3;                   // 0..63
    const int s   = (xcd << 2) | (jj & 3);     // 4 s-values per XCD -> X L2-resident
    const int o_base = (jj >> 2) * BN;         // 0..960

    const int lane = tid & 63, wv = tid >> 6;  // wv 0..7
    const int mwv = wv >> 1, nwv = wv & 1;     // 4M x 2N wave grid
    const int lr = lane & 15, kg = lane >> 4;

    // ---- staging bases ----
    const __bf16* Xbase = (const __bf16*)Xv + (size_t)s * kB * kIN;
    // eps/MS: GLDS #wv covers rows wv*8..wv*8+7; lane l -> row wv*8+(l>>3),
    // 16B-chunk (l&7)^((l>>3)&7)  => LDS holds (r*128 + c*16)^((r&7)<<4) swizzle
    const int erow = wv * 8 + (lane >> 3);
    const int ec16 = (lane & 7) ^ ((lane >> 3) & 7);
    const float*        Ebase = Ew + ((size_t)s * kOUT + o_base + erow) * kIN + ec16 * 4;
    const unsigned int* Mbase = MS + (size_t)(o_base + erow) * kIN + ec16 * 4;
    // fallback (fp32 X direct) base
    const float* Xgf = (const float*)Xv + ((size_t)s * kB + mwv * 64 + lr) * kIN + kg * 8;

    auto STAGE = [&](int t, int bf) {
        if constexpr (XBF) {
            #pragma unroll
            for (int q = 0; q < 2; ++q) {
                int row = wv * 32 + q * 16 + (lane >> 2);
                int qg  = ((lane & 3) - (row >> 2)) & 3;      // r0-verified rotation
                GLDS16(Xbase + (size_t)row * kIN + t * BK + qg * 8,
                       &Xs[bf][(wv * 32 + q * 16) * BK]);
            }
        }
        GLDS16(Ebase + t * BK, &Epb[bf][wv * 256]);
        GLDS16(Mbase + t * BK, &Msb[bf][wv * 256]);
    };

    v4f acc[4][2] = {};

    // ---- prologue: fill pipeline 2 deep ----
    STAGE(0, 0);
    STAGE(1, 1);

    for (int t = 0; t < NT; ++t) {
        const int bf = t % 3;

        // my ds_reads of buf[t-1] complete (reuse hazard) + my tile-t GLDS landed
        // (t+1's loads stay in flight: counted, never drained mid-loop)
        if (t < NT - 1) {
            if constexpr (XBF)
                asm volatile("s_waitcnt vmcnt(4) lgkmcnt(0)" ::: "memory");
            else
                asm volatile("s_waitcnt vmcnt(2) lgkmcnt(0)" ::: "memory");
        } else {
            asm volatile("s_waitcnt vmcnt(0) lgkmcnt(0)" ::: "memory");
        }
        __builtin_amdgcn_s_barrier();          // raw: no compiler vmcnt(0) drain

        if (t + 2 < NT) STAGE(t + 2, (t + 2) % 3);

        // ---- A frags ----
        v8bf a[4];
        if constexpr (XBF) {
            #pragma unroll
            for (int mf = 0; mf < 4; ++mf) {
                int row = mwv * 64 + mf * 16 + lr;
                int ql  = (kg + (row >> 2)) & 3;
                a[mf] = *reinterpret_cast<const v8bf*>(&Xs[bf][row * BK + ql * 8]);
            }
        } else {
            #pragma unroll
            for (int mf = 0; mf < 4; ++mf) {
                const float* xp = Xgf + (size_t)mf * 16 * kIN + t * BK;
                float4 x0 = *reinterpret_cast<const float4*>(xp);
                float4 x1 = *reinterpret_cast<const float4*>(xp + 4);
                v8bf tt;
                tt[0] = (__bf16)x0.x; tt[1] = (__bf16)x0.y;
                tt[2] = (__bf16)x0.z; tt[3] = (__bf16)x0.w;
                tt[4] = (__bf16)x1.x; tt[5] = (__bf16)x1.y;
                tt[6] = (__bf16)x1.z; tt[7] = (__bf16)x1.w;
                a[mf] = tt;
            }
        }

        // ---- B frags: read swizzled eps/MS, build W = mu + sigma*eps in-lane ----
        v8bf b[2];
        const char* eb = (const char*)&Epb[bf][0];
        const char* mb = (const char*)&Msb[bf][0];
        #pragma unroll
        for (int nf = 0; nf < 2; ++nf) {
            int r  = nwv * 32 + nf * 16 + lr;
            int o0 = (r * 128 + kg * 32) ^ ((r & 7) << 4);
            float4 e0 = *reinterpret_cast<const float4*>(eb + o0);
            float4 e1 = *reinterpret_cast<const float4*>(eb + (o0 ^ 16));
            uint4  p0 = *reinterpret_cast<const uint4*>(mb + o0);
            uint4  p1 = *reinterpret_cast<const uint4*>(mb + (o0 ^ 16));
            b[nf][0] = (__bf16)fmaf(asf(p0.x & 0xffff0000u), e0.x, asf(p0.x << 16));
            b[nf][1] = (__bf16)fmaf(asf(p0.y & 0xffff0000u), e0.y, asf(p0.y << 16));
            b[nf][2] = (__bf16)fmaf(asf(p0.z & 0xffff0000u), e0.z, asf(p0.z << 16));
            b[nf][3] = (__bf16)fmaf(asf(p0.w & 0xffff0000u), e0.w, asf(p0.w << 16));
            b[nf][4] = (__bf16)fmaf(asf(p1.x & 0xffff0000u), e1.x, asf(p1.x << 16));
            b[nf][5] = (__bf16)fmaf(asf(p1.y & 0xffff0000u), e1.y, asf(p1.y << 16));
            b[nf][6] = (__bf16)fmaf(asf(p1.z & 0xffff0000u), e1.z, asf(p1.z << 16));
            b[nf][7] = (__bf16)fmaf(asf(p1.w & 0xffff0000u), e1.w, asf(p1.w << 16));
        }

        // ---- 8 MFMAs ----
        #pragma unroll
        for (int mf = 0; mf < 4; ++mf)
            #pragma unroll
            for (int nf = 0; nf < 2; ++nf)
                acc[mf][nf] = __builtin_amdgcn_mfma_f32_16x16x32_bf16(
                    a[mf], b[nf], acc[mf][nf], 0, 0, 0);
    }

    // ---- epilogue: inline-sampled bias + nontemporal store ----
    float bias[2];
    #pragma unroll
    for (int nf = 0; nf < 2; ++nf) {
        int o = o_base + nwv * 32 + nf * 16 + lr;
        bias[nf] = fmaf(softplus_f(Brho[o]), Eb[(size_t)s * kOUT + o], Bmu[o]);
    }
    #pragma unroll
    for (int mf = 0; mf < 4; ++mf) {
        #pragma unroll
        for (int rr = 0; rr < 4; ++rr) {
            int mrow = mwv * 64 + mf * 16 + kg * 4 + rr;  // C/D: row=(lane>>4)*4+reg
            float* orow = O + ((size_t)s * kB + mrow) * kOUT + o_base + nwv * 32;
            #pragma unroll
            for (int nf = 0; nf < 2; ++nf)
                __builtin_nontemporal_store(acc[mf][nf][rr] + bias[nf],
                                            orow + nf * 16 + lr);  // col = lane&15
        }
    }
}

extern "C" void kernel_launch(void* const* d_in, const int* in_sizes, int n_in,
                              void* d_out, int out_size, void* d_ws, size_t ws_size,
                              hipStream_t stream) {
    const float* input = (const float*)d_in[0];
    const float* w_mu  = (const float*)d_in[1];
    const float* w_rho = (const float*)d_in[2];
    const float* b_mu  = (const float*)d_in[3];
    const float* b_rho = (const float*)d_in[4];
    const float* eps_w = (const float*)d_in[5];
    const float* eps_b = (const float*)d_in[6];
    float* out = (float*)d_out;

    const size_t ms_bytes  = (size_t)kOUT * kIN * 4;                 //  4 MB
    const size_t xbf_bytes = (size_t)kS * kB * kIN * sizeof(__bf16); // 16 MB
    const bool use_xbf = ws_size >= ms_bytes + xbf_bytes;

    unsigned int* ms = (unsigned int*)d_ws;
    __bf16* xbf = (__bf16*)((char*)d_ws + ms_bytes);

    sigma_pack<<<dim3((kOUT * kIN) / (256 * 4)), 256, 0, stream>>>(w_mu, w_rho, (uint4*)ms);

    dim3 grid(kS * (kOUT / BN));   // 512 blocks, XCD-swizzled (s pinned per XCD)
    if (use_xbf) {
        xcast_kernel<<<dim3((size_t)kS * kB * kIN / (256 * 8)), 256, 0, stream>>>(input, xbf);
        dv_main<true><<<grid, 512, 0, stream>>>(xbf, ms, eps_w, b_mu, b_rho, eps_b, out);
    } else {
        dv_main<false><<<grid, 512, 0, stream>>>(input, ms, eps_w, b_mu, b_rho, eps_b, out);
    }
}